// Round 3
// baseline (189.585 us; speedup 1.0000x reference)
//
#include <hip/hip_runtime.h>

#define IMG 512
#define NPLANES 48            // 16*3
#define TW 64                 // output tile width
#define TH 32                 // output tile height
#define RD 5
#define KW 11
#define VC (TW + 2*RD)        // 74 columns of vertical sums
#define WPAD 84               // 84%32=20 -> row bank-shifts {0,20,8,28}: max 2-way (free)
#define NTX (IMG/TW)          // 8
#define NTY (IMG/TH)          // 16
#define TPP (NTX*NTY)         // 128
#define NBLOCKS (NPLANES*TPP) // 6144
#define NPIX (16.0f*3.0f*512.0f*512.0f)

__device__ __forceinline__ float fast_rcp(float d) {
    float r = __builtin_amdgcn_rcpf(d);
    r = r * (2.0f - d * r);   // one Newton step: ~1e-7 rel error
    return r;
}

// symmetric 11-tap Gaussian
__device__ __forceinline__ float tap11(float x0, float x1, float x2, float x3,
                                       float x4, float x5, float x6, float x7,
                                       float x8, float x9, float x10) {
    return 0.00102838f*(x0+x10) + 0.00759876f*(x1+x9) + 0.03600077f*(x2+x8)
         + 0.10936069f*(x3+x7) + 0.21300553f*(x4+x6) + 0.26601172f*x5;
}

__global__ __launch_bounds__(256, 3) void ssim_kernel(
    const float* __restrict__ img1, const float* __restrict__ img2,
    float* __restrict__ out)
{
    // vertical windowed sums: mu1, mu2, E[aa], E[bb], E[ab]
    __shared__ float v[5][TH][WPAD];   // 53760 B
    __shared__ float wsum[4];

    const float cw[KW] = {
        0.00102838f, 0.00759876f, 0.03600077f, 0.10936069f, 0.21300553f,
        0.26601172f,
        0.21300553f, 0.10936069f, 0.03600077f, 0.00759876f, 0.00102838f
    };

    const int tid = threadIdx.x;
    const int blk = blockIdx.x;
    const int plane = blk / TPP;
    const int t     = blk % TPP;
    const int ty0 = (t / NTX) * TH;
    const int tx0 = (t % NTX) * TW;
    const float* __restrict__ p1 = img1 + (size_t)plane * IMG * IMG;
    const float* __restrict__ p2 = img2 + (size_t)plane * IMG * IMG;

    // block-uniform: no boundary clipping anywhere in the tile's halo?
    const bool interior = (tx0 != 0) && (tx0 != IMG - TW) &&
                          (ty0 != 0) && (ty0 != IMG - TH);

    // ---- pass 1: vertical 11-tap on raw + product images, global -> LDS ----
    // 296 tasks: (col 0..73) x (4 row-segments of 8 outputs)
    for (int task = tid; task < VC * 4; task += 256) {
        const int col = task % VC;       // storage column
        const int seg = task / VC;       // 0..3
        const int gx  = tx0 + col - RD;
        const int r0  = seg * 8;
        const int gy0 = ty0 + r0 - RD;

        float a[18], b[18];
        if (interior) {
            const float* __restrict__ pa = p1 + (size_t)gy0 * IMG + gx;
            const float* __restrict__ pb = p2 + (size_t)gy0 * IMG + gx;
            #pragma unroll
            for (int k = 0; k < 18; k++) {
                a[k] = pa[k * IMG];
                b[k] = pb[k * IMG];
            }
        } else {
            const bool xok = (gx >= 0) && (gx < IMG);
            #pragma unroll
            for (int k = 0; k < 18; k++) {
                const int gy = gy0 + k;
                const bool ok = xok && (gy >= 0) && (gy < IMG);
                const int gi = gy * IMG + gx;
                a[k] = ok ? p1[gi] : 0.f;
                b[k] = ok ? p2[gi] : 0.f;
            }
        }

        // transposed loop: products once per element, scatter to pending sums
        float s[8][5];
        #pragma unroll
        for (int o = 0; o < 8; o++)
            #pragma unroll
            for (int q = 0; q < 5; q++)
                s[o][q] = 0.f;

        #pragma unroll
        for (int k = 0; k < 18; k++) {
            const float av = a[k], bv = b[k];
            const float aa = av * av;
            const float bb = bv * bv;
            const float ab = av * bv;
            const int olo = (k - 10 < 0) ? 0 : k - 10;
            const int ohi = (k < 7) ? k : 7;
            #pragma unroll
            for (int o = olo; o <= ohi; o++) {
                const float w = cw[k - o];
                s[o][0] += w * av;
                s[o][1] += w * bv;
                s[o][2] += w * aa;
                s[o][3] += w * bb;
                s[o][4] += w * ab;
            }
        }

        #pragma unroll
        for (int o = 0; o < 8; o++) {
            const int r = r0 + o;
            v[0][r][col] = s[o][0];
            v[1][r][col] = s[o][1];
            v[2][r][col] = s[o][2];
            v[3][r][col] = s[o][3];
            v[4][r][col] = s[o][4];
        }
    }
    __syncthreads();

    // ---- pass 2: horizontal 11-tap (ds_read_b128, SSA scalars) + SSIM ----
    const float C1 = 1e-4f;
    const float C2 = 9e-4f;
    float acc = 0.f;
    #pragma unroll
    for (int it = 0; it < 2; it++) {
        const int task = tid + it * 256;     // 0..511
        const int j = task & 15;             // float4 group: outputs 4j..4j+3
        const int r = task >> 4;             // row 0..31
        float res[5][4];
        #pragma unroll
        for (int arr = 0; arr < 5; arr++) {
            const float4* row  = (const float4*)&v[arr][r][0];
            const float2* row2 = (const float2*)row;
            const float4 q0 = row[j + 0];
            const float4 q1 = row[j + 1];
            const float4 q2 = row[j + 2];
            const float2 q3 = row2[2*(j + 3)];
            res[arr][0] = tap11(q0.x,q0.y,q0.z,q0.w,q1.x,q1.y,q1.z,q1.w,q2.x,q2.y,q2.z);
            res[arr][1] = tap11(q0.y,q0.z,q0.w,q1.x,q1.y,q1.z,q1.w,q2.x,q2.y,q2.z,q2.w);
            res[arr][2] = tap11(q0.z,q0.w,q1.x,q1.y,q1.z,q1.w,q2.x,q2.y,q2.z,q2.w,q3.x);
            res[arr][3] = tap11(q0.w,q1.x,q1.y,q1.z,q1.w,q2.x,q2.y,q2.z,q2.w,q3.x,q3.y);
        }
        #pragma unroll
        for (int o = 0; o < 4; o++) {
            const float mu1 = res[0][o];
            const float mu2 = res[1][o];
            const float x11 = res[2][o];
            const float x22 = res[3][o];
            const float x12 = res[4][o];
            const float mu1s = mu1 * mu1;
            const float mu2s = mu2 * mu2;
            const float mu12 = mu1 * mu2;
            const float s1  = x11 - mu1s;
            const float s2  = x22 - mu2s;
            const float s12 = x12 - mu12;
            const float num = (2.f * mu12 + C1) * (2.f * s12 + C2);
            const float den = (mu1s + mu2s + C1) * (s1 + s2 + C2);
            acc += num * fast_rcp(den);
        }
    }

    // ---- block reduction + single atomic ----
    #pragma unroll
    for (int off = 32; off > 0; off >>= 1)
        acc += __shfl_down(acc, off, 64);
    const int lane = tid & 63;
    const int wv_i = tid >> 6;
    if (lane == 0) wsum[wv_i] = acc;
    __syncthreads();
    if (tid == 0) {
        const float total = (wsum[0] + wsum[1]) + (wsum[2] + wsum[3]);
        atomicAdd(out, total * (1.0f / NPIX));
    }
}

extern "C" void kernel_launch(void* const* d_in, const int* in_sizes, int n_in,
                              void* d_out, int out_size, void* d_ws, size_t ws_size,
                              hipStream_t stream) {
    const float* img1 = (const float*)d_in[0];
    const float* img2 = (const float*)d_in[1];
    float* out = (float*)d_out;

    hipMemsetAsync(out, 0, sizeof(float), stream);
    ssim_kernel<<<NBLOCKS, 256, 0, stream>>>(img1, img2, out);
}

// Round 4
// 185.907 us; speedup vs baseline: 1.0198x; 1.0198x over previous
//
#include <hip/hip_runtime.h>

#define IMG 512
#define NPLANES 48            // 16*3
#define TW 64                 // output tile width
#define TH 32                 // output tile height
#define RD 5
#define KW 11
#define VC (TW + 2*RD)        // 74 columns of vertical sums
#define WPAD 76               // row stride: 76*4=304 B, 16B-aligned; VC<=76
#define NTX (IMG/TW)          // 8
#define NTY (IMG/TH)          // 16
#define TPP (NTX*NTY)         // 128
#define NBLOCKS (NPLANES*TPP) // 6144
#define NPIX (16.0f*3.0f*512.0f*512.0f)

__device__ __forceinline__ float fast_rcp(float d) {
    float r = __builtin_amdgcn_rcpf(d);
    r = r * (2.0f - d * r);   // one Newton step: ~1e-7 rel error
    return r;
}

// symmetric 11-tap Gaussian
__device__ __forceinline__ float tap11(float x0, float x1, float x2, float x3,
                                       float x4, float x5, float x6, float x7,
                                       float x8, float x9, float x10) {
    return 0.00102838f*(x0+x10) + 0.00759876f*(x1+x9) + 0.03600077f*(x2+x8)
         + 0.10936069f*(x3+x7) + 0.21300553f*(x4+x6) + 0.26601172f*x5;
}

// LDS arrays: 0 = conv(u), 1 = conv(v), 2 = conv(u^2), 3 = conv(v^2)
// where u = a+b, v = a-b.  (4 streams instead of 5: SSIM only needs
// mu1, mu2, sigma1^2+sigma2^2, sigma12.)
__global__ __launch_bounds__(256, 4) void ssim_kernel(
    const float* __restrict__ img1, const float* __restrict__ img2,
    float* __restrict__ out)
{
    __shared__ float v[4][TH][WPAD];   // 38912 B -> 4 blocks/CU
    __shared__ float wsum[4];

    const float cw[KW] = {
        0.00102838f, 0.00759876f, 0.03600077f, 0.10936069f, 0.21300553f,
        0.26601172f,
        0.21300553f, 0.10936069f, 0.03600077f, 0.00759876f, 0.00102838f
    };

    const int tid = threadIdx.x;
    const int blk = blockIdx.x;
    const int plane = blk / TPP;
    const int t     = blk % TPP;
    const int ty0 = (t / NTX) * TH;
    const int tx0 = (t % NTX) * TW;
    const float* __restrict__ p1 = img1 + (size_t)plane * IMG * IMG;
    const float* __restrict__ p2 = img2 + (size_t)plane * IMG * IMG;

    const bool interior = (tx0 != 0) && (tx0 != IMG - TW) &&
                          (ty0 != 0) && (ty0 != IMG - TH);

    // ---- pass 1: vertical 11-tap on u, v, u^2, v^2 -> LDS ----
    // 296 tasks: (col 0..73) x (4 row-segments of 8 outputs)
    for (int task = tid; task < VC * 4; task += 256) {
        const int col = task % VC;
        const int seg = task / VC;
        const int gx  = tx0 + col - RD;
        const int r0  = seg * 8;
        const int gy0 = ty0 + r0 - RD;

        float a[18], b[18];
        if (interior) {
            const float* __restrict__ pa = p1 + (size_t)gy0 * IMG + gx;
            const float* __restrict__ pb = p2 + (size_t)gy0 * IMG + gx;
            #pragma unroll
            for (int k = 0; k < 18; k++) {
                a[k] = pa[k * IMG];
                b[k] = pb[k * IMG];
            }
        } else {
            const bool xok = (gx >= 0) && (gx < IMG);
            #pragma unroll
            for (int k = 0; k < 18; k++) {
                const int gy = gy0 + k;
                const bool ok = xok && (gy >= 0) && (gy < IMG);
                const int gi = gy * IMG + gx;
                a[k] = ok ? p1[gi] : 0.f;
                b[k] = ok ? p2[gi] : 0.f;
            }
        }

        float s[8][4];
        #pragma unroll
        for (int o = 0; o < 8; o++)
            #pragma unroll
            for (int q = 0; q < 4; q++)
                s[o][q] = 0.f;

        #pragma unroll
        for (int k = 0; k < 18; k++) {
            const float uu = a[k] + b[k];
            const float vv = a[k] - b[k];
            const float u2 = uu * uu;
            const float v2 = vv * vv;
            const int olo = (k - 10 < 0) ? 0 : k - 10;
            const int ohi = (k < 7) ? k : 7;
            #pragma unroll
            for (int o = olo; o <= ohi; o++) {
                const float w = cw[k - o];
                s[o][0] += w * uu;
                s[o][1] += w * vv;
                s[o][2] += w * u2;
                s[o][3] += w * v2;
            }
        }

        #pragma unroll
        for (int o = 0; o < 8; o++) {
            const int r = r0 + o;
            v[0][r][col] = s[o][0];
            v[1][r][col] = s[o][1];
            v[2][r][col] = s[o][2];
            v[3][r][col] = s[o][3];
        }
    }
    __syncthreads();

    // ---- pass 2: horizontal 11-tap (ds_read_b128) + SSIM ----
    const float C1 = 1e-4f;
    const float C2 = 9e-4f;
    float acc = 0.f;
    #pragma unroll
    for (int it = 0; it < 2; it++) {
        const int task = tid + it * 256;     // 0..511
        const int j = task & 15;             // outputs 4j..4j+3
        const int r = task >> 4;             // row 0..31
        float res[4][4];
        #pragma unroll
        for (int arr = 0; arr < 4; arr++) {
            const float4* row  = (const float4*)&v[arr][r][0];
            const float2* row2 = (const float2*)row;
            const float4 q0 = row[j + 0];
            const float4 q1 = row[j + 1];
            const float4 q2 = row[j + 2];
            const float2 q3 = row2[2*(j + 3)];
            res[arr][0] = tap11(q0.x,q0.y,q0.z,q0.w,q1.x,q1.y,q1.z,q1.w,q2.x,q2.y,q2.z);
            res[arr][1] = tap11(q0.y,q0.z,q0.w,q1.x,q1.y,q1.z,q1.w,q2.x,q2.y,q2.z,q2.w);
            res[arr][2] = tap11(q0.z,q0.w,q1.x,q1.y,q1.z,q1.w,q2.x,q2.y,q2.z,q2.w,q3.x);
            res[arr][3] = tap11(q0.w,q1.x,q1.y,q1.z,q1.w,q2.x,q2.y,q2.z,q2.w,q3.x,q3.y);
        }
        #pragma unroll
        for (int o = 0; o < 4; o++) {
            const float U = res[0][o];   // mu1+mu2
            const float V = res[1][o];   // mu1-mu2
            const float P = res[2][o];   // E[(a+b)^2]
            const float Q = res[3][o];   // E[(a-b)^2]
            const float p2 = U * U;
            const float q2 = V * V;
            const float mu12_2 = (p2 - q2) * 0.5f;   // 2*mu1*mu2
            const float musq   = (p2 + q2) * 0.5f;   // mu1^2+mu2^2
            const float e_sum  = (P + Q) * 0.5f;     // E[aa]+E[bb]
            const float e_dif  = (P - Q) * 0.5f;     // 2*E[ab]
            const float sigsum = e_sum - musq;       // s1^2+s2^2
            const float sig122 = e_dif - mu12_2;     // 2*s12
            const float num = (mu12_2 + C1) * (sig122 + C2);
            const float den = (musq + C1) * (sigsum + C2);
            acc += num * fast_rcp(den);
        }
    }

    // ---- block reduction + single atomic ----
    #pragma unroll
    for (int off = 32; off > 0; off >>= 1)
        acc += __shfl_down(acc, off, 64);
    const int lane = tid & 63;
    const int wv_i = tid >> 6;
    if (lane == 0) wsum[wv_i] = acc;
    __syncthreads();
    if (tid == 0) {
        const float total = (wsum[0] + wsum[1]) + (wsum[2] + wsum[3]);
        atomicAdd(out, total * (1.0f / NPIX));
    }
}

extern "C" void kernel_launch(void* const* d_in, const int* in_sizes, int n_in,
                              void* d_out, int out_size, void* d_ws, size_t ws_size,
                              hipStream_t stream) {
    const float* img1 = (const float*)d_in[0];
    const float* img2 = (const float*)d_in[1];
    float* out = (float*)d_out;

    hipMemsetAsync(out, 0, sizeof(float), stream);
    ssim_kernel<<<NBLOCKS, 256, 0, stream>>>(img1, img2, out);
}

// Round 5
// 185.149 us; speedup vs baseline: 1.0240x; 1.0041x over previous
//
#include <hip/hip_runtime.h>

typedef float f2 __attribute__((ext_vector_type(2)));

#define IMG 512
#define NPLANES 48            // 16*3
#define TW 64                 // output tile width
#define TH 32                 // output tile height
#define RD 5
#define KW 11
#define WPAD 76               // flat row stride (floats), 16B-aligned rows
#define NPAIRS 38             // column pairs in pass 1 (cols -1..74)
#define NTX (IMG/TW)          // 8
#define NTY (IMG/TH)          // 16
#define TPP (NTX*NTY)         // 128
#define NBLOCKS (NPLANES*TPP) // 6144
#define NPIX (16.0f*3.0f*512.0f*512.0f)

__device__ __forceinline__ f2 mk(float a, float b) { f2 r; r.x = a; r.y = b; return r; }

__device__ __forceinline__ f2 rcp2(f2 d) {
    f2 r;
    r.x = __builtin_amdgcn_rcpf(d.x);
    r.y = __builtin_amdgcn_rcpf(d.y);
    r = r * (2.0f - d * r);   // packed Newton step
    return r;
}

// packed horizontal 11-tap: returns {conv@x[5-5..], conv@x+1} from 12 floats
__device__ __forceinline__ f2 tap11p(const float* x) {
    f2 r = mk(x[5], x[6]) * 0.26601172f;
    r += (mk(x[0], x[1]) + mk(x[10], x[11])) * 0.00102838f;
    r += (mk(x[1], x[2]) + mk(x[9],  x[10])) * 0.00759876f;
    r += (mk(x[2], x[3]) + mk(x[8],  x[9]))  * 0.03600077f;
    r += (mk(x[3], x[4]) + mk(x[7],  x[8]))  * 0.10936069f;
    r += (mk(x[4], x[5]) + mk(x[6],  x[7]))  * 0.21300553f;
    return r;
}

// LDS streams: 0=conv(u), 1=conv(v), 2=conv(u^2), 3=conv(v^2); u=a+b, v=a-b
__global__ __launch_bounds__(256) void ssim_kernel(
    const float* __restrict__ img1, const float* __restrict__ img2,
    float* __restrict__ out)
{
    __shared__ __align__(16) float v[4][TH][WPAD];   // 38912 B
    __shared__ float wsum[4];

    const float cw[KW] = {
        0.00102838f, 0.00759876f, 0.03600077f, 0.10936069f, 0.21300553f,
        0.26601172f,
        0.21300553f, 0.10936069f, 0.03600077f, 0.00759876f, 0.00102838f
    };

    const int tid = threadIdx.x;
    const int blk = blockIdx.x;
    const int plane = blk / TPP;
    const int t     = blk % TPP;
    const int ty0 = (t / NTX) * TH;
    const int tx0 = (t % NTX) * TW;
    const float* __restrict__ p1 = img1 + (size_t)plane * IMG * IMG;
    const float* __restrict__ p2 = img2 + (size_t)plane * IMG * IMG;

    const bool interior = (tx0 != 0) && (tx0 != IMG - TW) &&
                          (ty0 != 0) && (ty0 != IMG - TH);

    // ---- pass 1: vertical 11-tap on u,v,u2,v2 for adjacent col-pairs ----
    // 152 tasks: 38 col-pairs x 4 row-segments (8 outputs from 18 rows)
    if (tid < NPAIRS * 4) {
        const int pp  = tid % NPAIRS;
        const int seg = tid / NPAIRS;
        const int c0  = 2 * pp - 1;           // storage col of lo half (-1..73)
        const int gx0 = tx0 + c0 - RD;        // EVEN -> 8B-aligned f2 loads
        const int r0  = seg * 8;
        const int gy0 = ty0 + r0 - RD;

        f2 a[18], b[18];
        if (interior) {
            const f2* __restrict__ pa = (const f2*)(p1 + (size_t)gy0 * IMG + gx0);
            const f2* __restrict__ pb = (const f2*)(p2 + (size_t)gy0 * IMG + gx0);
            #pragma unroll
            for (int k = 0; k < 18; k++) {
                a[k] = pa[k * (IMG / 2)];
                b[k] = pb[k * (IMG / 2)];
            }
        } else {
            const int gxL = gx0, gxR = gx0 + 1;
            const bool okL = (gxL >= 0) && (gxL < IMG);
            const bool okR = (gxR >= 0) && (gxR < IMG);
            #pragma unroll
            for (int k = 0; k < 18; k++) {
                const int gy = gy0 + k;
                const bool rok = (gy >= 0) && (gy < IMG);
                const int base = gy * IMG;
                a[k].x = (rok && okL) ? p1[base + gxL] : 0.f;
                a[k].y = (rok && okR) ? p1[base + gxR] : 0.f;
                b[k].x = (rok && okL) ? p2[base + gxL] : 0.f;
                b[k].y = (rok && okR) ? p2[base + gxR] : 0.f;
            }
        }

        f2 s[8][4];
        #pragma unroll
        for (int o = 0; o < 8; o++)
            #pragma unroll
            for (int q = 0; q < 4; q++)
                s[o][q] = mk(0.f, 0.f);

        #pragma unroll
        for (int k = 0; k < 18; k++) {
            const f2 uu = a[k] + b[k];
            const f2 vv = a[k] - b[k];
            const f2 u2 = uu * uu;
            const f2 v2 = vv * vv;
            const int olo = (k - 10 < 0) ? 0 : k - 10;
            const int ohi = (k < 7) ? k : 7;
            #pragma unroll
            for (int o = olo; o <= ohi; o++) {
                const float w = cw[k - o];
                s[o][0] += uu * w;
                s[o][1] += vv * w;
                s[o][2] += u2 * w;
                s[o][3] += v2 * w;
            }
        }

        #pragma unroll
        for (int o = 0; o < 8; o++) {
            const int r = r0 + o;
            #pragma unroll
            for (int arr = 0; arr < 4; arr++) {
                if (c0 >= 0) v[arr][r][c0] = s[o][arr].x;
                v[arr][r][c0 + 1] = s[o][arr].y;   // col 74 is pad, never read
            }
        }
    }
    __syncthreads();

    // ---- pass 2: horizontal 11-tap, outputs packed as float2 pairs ----
    const float C1 = 1e-4f;
    const float C2 = 9e-4f;
    f2 acc2 = mk(0.f, 0.f);
    #pragma unroll
    for (int it = 0; it < 2; it++) {
        const int task = tid + it * 256;     // 0..511
        const int j = task & 15;             // outputs 4j..4j+3
        const int r = task >> 4;             // row 0..31
        f2 resA[4], resB[4];
        #pragma unroll
        for (int arr = 0; arr < 4; arr++) {
            const float* row = &v[arr][r][0];
            const float4 q0 = *(const float4*)(row + 4 * j);
            const float4 q1 = *(const float4*)(row + 4 * j + 4);
            const float4 q2 = *(const float4*)(row + 4 * j + 8);
            const float2 q3 = *(const float2*)(row + 4 * j + 12);
            const float x[14] = { q0.x, q0.y, q0.z, q0.w,
                                  q1.x, q1.y, q1.z, q1.w,
                                  q2.x, q2.y, q2.z, q2.w,
                                  q3.x, q3.y };
            resA[arr] = tap11p(x);       // outputs 4j, 4j+1
            resB[arr] = tap11p(x + 2);   // outputs 4j+2, 4j+3
        }
        #pragma unroll
        for (int h = 0; h < 2; h++) {
            const f2 U = h ? resB[0] : resA[0];
            const f2 V = h ? resB[1] : resA[1];
            const f2 P = h ? resB[2] : resA[2];
            const f2 Q = h ? resB[3] : resA[3];
            const f2 p2 = U * U;
            const f2 q2 = V * V;
            const f2 mu12_2 = (p2 - q2) * 0.5f;   // 2*mu1*mu2
            const f2 musq   = (p2 + q2) * 0.5f;   // mu1^2+mu2^2
            const f2 e_sum  = (P + Q) * 0.5f;     // E[aa]+E[bb]
            const f2 e_dif  = (P - Q) * 0.5f;     // 2*E[ab]
            const f2 sigsum = e_sum - musq;       // s1^2+s2^2
            const f2 sig122 = e_dif - mu12_2;     // 2*s12
            const f2 num = (mu12_2 + C1) * (sig122 + C2);
            const f2 den = (musq + C1) * (sigsum + C2);
            acc2 += num * rcp2(den);
        }
    }

    // ---- block reduction + single atomic ----
    float acc = acc2.x + acc2.y;
    #pragma unroll
    for (int off = 32; off > 0; off >>= 1)
        acc += __shfl_down(acc, off, 64);
    const int lane = tid & 63;
    const int wv_i = tid >> 6;
    if (lane == 0) wsum[wv_i] = acc;
    __syncthreads();
    if (tid == 0) {
        const float total = (wsum[0] + wsum[1]) + (wsum[2] + wsum[3]);
        atomicAdd(out, total * (1.0f / NPIX));
    }
}

extern "C" void kernel_launch(void* const* d_in, const int* in_sizes, int n_in,
                              void* d_out, int out_size, void* d_ws, size_t ws_size,
                              hipStream_t stream) {
    const float* img1 = (const float*)d_in[0];
    const float* img2 = (const float*)d_in[1];
    float* out = (float*)d_out;

    hipMemsetAsync(out, 0, sizeof(float), stream);
    ssim_kernel<<<NBLOCKS, 256, 0, stream>>>(img1, img2, out);
}